// Round 4
// baseline (156.106 us; speedup 1.0000x reference)
//
#include <hip/hip_runtime.h>
#include <hip/hip_bf16.h>
#include <stdint.h>

typedef __attribute__((ext_vector_type(8))) short s16x8;
typedef __attribute__((ext_vector_type(8))) unsigned short u16x8;
typedef __attribute__((ext_vector_type(4))) float f32x4;

#define SEQ 2048
#define LOG2E 1.44269504088896f

__device__ __forceinline__ unsigned short f2b(float x) {
  union { __hip_bfloat16 h; unsigned short u; } cv;
  cv.h = __float2bfloat16(x);
  return cv.u;
}

__device__ __forceinline__ float exp2fast(float x) {
  float r;
  asm("v_exp_f32 %0, %1" : "=v"(r) : "v"(x));
  return r;
}

__device__ __forceinline__ void gload16(const void* g, void* l) {
  __builtin_amdgcn_global_load_lds(
      (const __attribute__((address_space(1))) void*)g,
      (__attribute__((address_space(3))) void*)l, 16, 0, 0);
}

__global__ void cvt_f32_bf16(const float* __restrict__ in,
                             __hip_bfloat16* __restrict__ out, int n4) {
  int i = blockIdx.x * blockDim.x + threadIdx.x;
  if (i >= n4) return;
  float4 v = reinterpret_cast<const float4*>(in)[i];
  ushort4 o;
  o.x = f2b(v.x); o.y = f2b(v.y); o.z = f2b(v.z); o.w = f2b(v.w);
  reinterpret_cast<ushort4*>(out)[i] = o;
}

// C = A[M,K] * B^T (B is [N,K] row-major), + bias[N]
template <int MODE>
__global__ __launch_bounds__(256) void gemm_bt(
    const __hip_bfloat16* __restrict__ A, const __hip_bfloat16* __restrict__ B,
    const float* __restrict__ bias, void* __restrict__ Cout,
    __hip_bfloat16* __restrict__ Vt, int M, int N, int K) {
  __shared__ __align__(16) __hip_bfloat16 As[128 * 32];
  __shared__ __align__(16) __hip_bfloat16 Bs[128 * 32];
  const int tid = threadIdx.x;
  const int lane = tid & 63;
  const int w = tid >> 6;
  const int wr = w >> 1, wc = w & 1;
  const int rowg = blockIdx.x * 128;
  const int colg = blockIdx.y * 128;
  const int lr = lane & 15;
  const int lk = (lane >> 4) * 8;
  f32x4 acc[4][4];
#pragma unroll
  for (int m = 0; m < 4; ++m)
#pragma unroll
    for (int n = 0; n < 4; ++n) acc[m][n] = (f32x4){0.f, 0.f, 0.f, 0.f};
  for (int kt = 0; kt < K; kt += 32) {
#pragma unroll
    for (int r = 0; r < 2; ++r) {
      const int idx = r * 256 + tid;
      const int row = idx >> 2;
      const int ko = (idx & 3) * 8;
      gload16(A + (size_t)(rowg + row) * K + kt + ko, As + idx * 8);
      gload16(B + (size_t)(colg + row) * K + kt + ko, Bs + idx * 8);
    }
    __syncthreads();
    s16x8 af[4], bfr[4];
#pragma unroll
    for (int m = 0; m < 4; ++m)
      af[m] = *reinterpret_cast<const s16x8*>(As + (wr * 64 + m * 16 + lr) * 32 + lk);
#pragma unroll
    for (int n = 0; n < 4; ++n)
      bfr[n] = *reinterpret_cast<const s16x8*>(Bs + (wc * 64 + n * 16 + lr) * 32 + lk);
#pragma unroll
    for (int m = 0; m < 4; ++m)
#pragma unroll
      for (int n = 0; n < 4; ++n)
        acc[m][n] = __builtin_amdgcn_mfma_f32_16x16x32_bf16(af[m], bfr[n], acc[m][n], 0, 0, 0);
    __syncthreads();
  }
  const int r0l = (lane >> 4) * 4;
#pragma unroll
  for (int m = 0; m < 4; ++m) {
#pragma unroll
    for (int n = 0; n < 4; ++n) {
      const int col = colg + wc * 64 + n * 16 + lr;
      const int row0 = rowg + wr * 64 + m * 16 + r0l;
      const float bv = bias[col];
      if (MODE == 0) {
        if (col < 2048) {
          __hip_bfloat16* qkb = (__hip_bfloat16*)Cout;
#pragma unroll
          for (int j = 0; j < 4; ++j)
            qkb[(size_t)(row0 + j) * 2048 + col] = __float2bfloat16(acc[m][n][j] + bv);
        } else {
          const int c2 = col - 2048;
          const int bb = row0 >> 11;
          const int s0 = row0 & 2047;
          ushort4 pk;
          unsigned short* pp = (unsigned short*)&pk;
#pragma unroll
          for (int j = 0; j < 4; ++j) pp[j] = f2b(acc[m][n][j] + bv);
          *reinterpret_cast<ushort4*>(
              Vt + ((size_t)(bb * 16 + (c2 >> 6)) * 64 + (c2 & 63)) * 2048 + s0) = pk;
        }
      } else {
        float* o = (float*)Cout;
#pragma unroll
        for (int j = 0; j < 4; ++j)
          o[(size_t)(row0 + j) * N + col] = acc[m][n][j] + bv;
      }
    }
  }
}

// XOR swizzle for [rows][128B] LDS tiles
__device__ __forceinline__ int swz(int row, int byteInRow) {
  return row * 128 + (byteInRow ^ ((row & 7) << 4));
}

// Swapped-operand attention tile: S' = mfma(K, Q) -> [kv, q] layout.
// Each lane owns ONE q column (q = lane&15): softmax state m/l is a per-lane
// scalar; row reductions = in-lane tree + 2 shfl_xor (vs 16 shuffles).
__device__ __forceinline__ void attn_tile(
    const char* Ks, const char* Vs, char* pw, const float* Bm,
    s16x8 aq0, s16x8 aq1, int lane, int kv0, int q_abs, bool causal,
    float& m_r, float& l_r, f32x4* oa) {
  const int lr = lane & 15;
  const int g = lane >> 4;
  const int lkB = g * 16;
  const float SCALE2 = 0.125f * LOG2E;
  f32x4 sf[4];
#pragma unroll
  for (int n = 0; n < 4; ++n) {
    s16x8 ak0 = *reinterpret_cast<const s16x8*>(Ks + swz(n * 16 + lr, lkB));
    s16x8 ak1 = *reinterpret_cast<const s16x8*>(Ks + swz(n * 16 + lr, 64 + lkB));
    f32x4 z = (f32x4){0.f, 0.f, 0.f, 0.f};
    z = __builtin_amdgcn_mfma_f32_16x16x32_bf16(ak0, aq0, z, 0, 0, 0);
    z = __builtin_amdgcn_mfma_f32_16x16x32_bf16(ak1, aq1, z, 0, 0, 0);
    sf[n] = z;  // sf[n][j]: kv = kv0 + n*16 + g*4 + j, q = q_abs
  }
#pragma unroll
  for (int n = 0; n < 4; ++n) {
    f32x4 bv = *reinterpret_cast<const f32x4*>(Bm + n * 16 + g * 4);
#pragma unroll
    for (int j = 0; j < 4; ++j) sf[n][j] = fmaf(sf[n][j], SCALE2, bv[j]);
  }
  if (causal) {
    const int kvb = kv0 + g * 4;
#pragma unroll
    for (int n = 0; n < 4; ++n)
#pragma unroll
      for (int j = 0; j < 4; ++j)
        if (kvb + n * 16 + j > q_abs) sf[n][j] = -1e30f;
  }
  // in-lane row max tree + 2 shfl
  float mx[4];
#pragma unroll
  for (int n = 0; n < 4; ++n)
    mx[n] = fmaxf(fmaxf(sf[n][0], sf[n][1]), fmaxf(sf[n][2], sf[n][3]));
  float tm = fmaxf(fmaxf(mx[0], mx[1]), fmaxf(mx[2], mx[3]));
  tm = fmaxf(tm, __shfl_xor(tm, 16));
  tm = fmaxf(tm, __shfl_xor(tm, 32));
  const float mn = fmaxf(m_r, tm);
  const float al = exp2fast(m_r - mn);
  m_r = mn;
  float ps[4];
#pragma unroll
  for (int n = 0; n < 4; ++n) {
#pragma unroll
    for (int j = 0; j < 4; ++j) sf[n][j] = exp2fast(sf[n][j] - mn);
    ps[n] = (sf[n][0] + sf[n][1]) + (sf[n][2] + sf[n][3]);
  }
  float rs = (ps[0] + ps[1]) + (ps[2] + ps[3]);
  rs += __shfl_xor(rs, 16);
  rs += __shfl_xor(rs, 32);
  l_r = l_r * al + rs;
  // rescale O (oa rows are q = g*4+j -> fetch al per row via shfl)
  float alj[4];
#pragma unroll
  for (int j = 0; j < 4; ++j) alj[j] = __shfl(al, g * 4 + j);
#pragma unroll
  for (int d = 0; d < 4; ++d)
#pragma unroll
    for (int j = 0; j < 4; ++j) oa[d][j] *= alj[j];
  // pack P row fragment (4 bf16 = 8B per n) and write to per-wave LDS
#pragma unroll
  for (int n = 0; n < 4; ++n) {
    union { ushort4 u; uint2 v; } pk;
    pk.u.x = f2b(sf[n][0]); pk.u.y = f2b(sf[n][1]);
    pk.u.z = f2b(sf[n][2]); pk.u.w = f2b(sf[n][3]);
    *reinterpret_cast<uint2*>(pw + lr * 128 + ((n * 32 + g * 8) ^ ((lr & 7) << 4))) = pk.v;
  }
  s16x8 pa0 = *reinterpret_cast<const s16x8*>(pw + swz(lr, lkB));
  s16x8 pa1 = *reinterpret_cast<const s16x8*>(pw + swz(lr, 64 + lkB));
#pragma unroll
  for (int d = 0; d < 4; ++d) {
    s16x8 bv0 = *reinterpret_cast<const s16x8*>(Vs + swz(d * 16 + lr, lkB));
    s16x8 bv1 = *reinterpret_cast<const s16x8*>(Vs + swz(d * 16 + lr, 64 + lkB));
    oa[d] = __builtin_amdgcn_mfma_f32_16x16x32_bf16(pa0, bv0, oa[d], 0, 0, 0);
    oa[d] = __builtin_amdgcn_mfma_f32_16x16x32_bf16(pa1, bv1, oa[d], 0, 0, 0);
  }
}

__device__ __forceinline__ void write_O(__hip_bfloat16* O, int b, int h, int row0,
                                        int lane, float l_r, const f32x4* oa) {
  const int lr = lane & 15, g = lane >> 4;
  const float linv = 1.0f / l_r;
  float li[4];
#pragma unroll
  for (int j = 0; j < 4; ++j) li[j] = __shfl(linv, g * 4 + j);
#pragma unroll
  for (int d = 0; d < 4; ++d)
#pragma unroll
    for (int j = 0; j < 4; ++j)
      O[(size_t)(b * SEQ + row0 + g * 4 + j) * 1024 + h * 64 + d * 16 + lr] =
          __float2bfloat16(oa[d][j] * li[j]);
}

// Uniform-work causal attention. Block = q-tile pair (p, 31-p), 8 waves.
// Group A (waves 0-3): heavy tile (31-p), kv tiles 0..15.
// Group B (waves 4-7): light tile (p), kv 0..p (writes light output), then
// heavy tile kv 16..31-p. Every block runs exactly 17 iterations. Heavy
// partials (A,B) merge at the end via LDS online-softmax combine.
__global__ __launch_bounds__(512) void attn_fwd(
    const __hip_bfloat16* __restrict__ qk, const __hip_bfloat16* __restrict__ Vt,
    const float* __restrict__ abias, const void* __restrict__ maskp,
    __hip_bfloat16* __restrict__ O) {
  __shared__ __align__(16) char KV[2][2][64 * 128];  // [group][K|V]
  __shared__ __align__(16) char Ps[8][16 * 128];     // per-wave P; merge area after loop
  __shared__ float Bm[2][64];
  __shared__ float mlArr[4][2][16];
  const int tid = threadIdx.x;
  const int lane = tid & 63;
  const int w = tid >> 6;
  const int wsub = w & 3;
  const bool isB = (w >= 4);
  const int p = blockIdx.x;
  const int bh = blockIdx.y;
  const int b = bh >> 4, h = bh & 15;
  const int lr = lane & 15;
  const int g = lane >> 4;
  // mask format probe
  const int* mi = (const int*)maskp;
  const unsigned char* mbyte = (const unsigned char*)maskp;
  const bool int_fmt = (mi[0] == 0 || mi[0] == 1);
  // ---- per-wave q-tile state ----
  int qt = isB ? p : (31 - p);
  int row0 = qt * 64 + wsub * 16;
  int q_abs = row0 + lr;
  const __hip_bfloat16* qbase = qk + (size_t)b * SEQ * 2048 + h * 64 + g * 8;
  s16x8 aq0 = *reinterpret_cast<const s16x8*>(qbase + (size_t)(row0 + lr) * 2048);
  s16x8 aq1 = *reinterpret_cast<const s16x8*>(qbase + (size_t)(row0 + lr) * 2048 + 32);
  float m_r = -INFINITY, l_r = 0.f;
  f32x4 oa[4];
#pragma unroll
  for (int d = 0; d < 4; ++d) oa[d] = (f32x4){0.f, 0.f, 0.f, 0.f};
  // ---- staging (per group: 256 threads stage 64rows x 128B K and V) ----
  const int grp = tid >> 8;  // 0 = A, 1 = B
  const int gi = tid & 255;
  const int r0s = gi >> 3;        // rows r0s and r0s+32
  const int c8 = gi & 7;          // 16B chunk in row
  char* myK = KV[grp][0];
  char* myV = KV[grp][1];
  const __hip_bfloat16* kbase = qk + (size_t)b * SEQ * 2048 + 1024 + h * 64 + c8 * 8;
  const __hip_bfloat16* vbase = Vt + (size_t)(bh * 64) * 2048 + c8 * 8;
  u16x8 kp0, kp1, vp0, vp1;
  float bmv = 0.f;
#define KVT(T) ((grp == 0) ? (T) : (((T) <= p) ? (T) : ((T) + 15 - p)))
#define ISSUE(KVT_)                                                              \
  {                                                                              \
    const int kv0_ = (KVT_) * 64;                                                \
    kp0 = *reinterpret_cast<const u16x8*>(kbase + (size_t)(kv0_ + r0s) * 2048);  \
    kp1 = *reinterpret_cast<const u16x8*>(kbase + (size_t)(kv0_ + r0s + 32) * 2048); \
    vp0 = *reinterpret_cast<const u16x8*>(vbase + (size_t)r0s * 2048 + kv0_);    \
    vp1 = *reinterpret_cast<const u16x8*>(vbase + (size_t)(r0s + 32) * 2048 + kv0_); \
    if (gi < 64) {                                                               \
      const int kv_ = kv0_ + gi;                                                 \
      const bool ok_ =                                                           \
          int_fmt ? (mi[b * SEQ + kv_] != 0) : (mbyte[b * SEQ + kv_] != 0);      \
      bmv = ok_ ? abias[h * SEQ + kv_] * LOG2E : -1e30f;                         \
    }                                                                            \
  }
  ISSUE(KVT(0));
  for (int t = 0; t < 17; ++t) {
    const bool act = isB || (t < 16);  // A has no tile at t=16
    __syncthreads();                   // all waves done reading prev K/V
    if (act) {
      *reinterpret_cast<u16x8*>(myK + swz(r0s, c8 * 16)) = kp0;
      *reinterpret_cast<u16x8*>(myK + swz(r0s + 32, c8 * 16)) = kp1;
      *reinterpret_cast<u16x8*>(myV + swz(r0s, c8 * 16)) = vp0;
      *reinterpret_cast<u16x8*>(myV + swz(r0s + 32, c8 * 16)) = vp1;
      if (gi < 64) Bm[grp][gi] = bmv;
    }
    __syncthreads();
    if (isB ? (t + 1 <= 16) : (t + 1 < 16)) ISSUE(KVT(t + 1));
    if (act) {
      const int kvt = isB ? ((t <= p) ? t : (t + 15 - p)) : t;
      const bool causal = isB && (t == p || t == 16);
      attn_tile(KV[grp][0], KV[grp][1], Ps[w], Bm[grp], aq0, aq1, lane,
                kvt * 64, q_abs, causal, m_r, l_r, oa);
    }
    if (isB && t == p) {
      // light tile complete: write its output, switch to heavy partial
      write_O(O, b, h, row0, lane, l_r, oa);
      qt = 31 - p;
      row0 = qt * 64 + wsub * 16;
      q_abs = row0 + lr;
      aq0 = *reinterpret_cast<const s16x8*>(qbase + (size_t)(row0 + lr) * 2048);
      aq1 = *reinterpret_cast<const s16x8*>(qbase + (size_t)(row0 + lr) * 2048 + 32);
      m_r = -INFINITY; l_r = 0.f;
#pragma unroll
      for (int d = 0; d < 4; ++d) oa[d] = (f32x4){0.f, 0.f, 0.f, 0.f};
    }
  }
#undef ISSUE
#undef KVT
  // ---- merge heavy partials: B(wave w+4) into A(wave w) ----
  __syncthreads();  // everyone done with Ps as P-buffer
  if (isB) {
    float* mo = (float*)(&Ps[0][0] + wsub * 4096);
#pragma unroll
    for (int d = 0; d < 4; ++d)
#pragma unroll
      for (int j = 0; j < 4; ++j)
        mo[(g * 4 + j) * 64 + d * 16 + lr] = oa[d][j];
    if (lane < 16) {
      mlArr[wsub][0][lr] = m_r;
      mlArr[wsub][1][lr] = l_r;
    }
  }
  __syncthreads();
  if (!isB) {
    const float mB = mlArr[wsub][0][lr];
    const float lB = mlArr[wsub][1][lr];
    const float mS = fmaxf(m_r, mB);
    const float fA = exp2fast(m_r - mS);
    const float fB = exp2fast(mB - mS);
    const float linv = 1.0f / (l_r * fA + lB * fB);
    float fAj[4], fBj[4], lij[4];
#pragma unroll
    for (int j = 0; j < 4; ++j) {
      fAj[j] = __shfl(fA, g * 4 + j);
      fBj[j] = __shfl(fB, g * 4 + j);
      lij[j] = __shfl(linv, g * 4 + j);
    }
    const float* mo = (const float*)(&Ps[0][0] + wsub * 4096);
#pragma unroll
    for (int d = 0; d < 4; ++d)
#pragma unroll
      for (int j = 0; j < 4; ++j) {
        const float v =
            (oa[d][j] * fAj[j] + mo[(g * 4 + j) * 64 + d * 16 + lr] * fBj[j]) * lij[j];
        O[(size_t)(b * SEQ + row0 + g * 4 + j) * 1024 + h * 64 + d * 16 + lr] =
            __float2bfloat16(v);
      }
  }
}

extern "C" void kernel_launch(void* const* d_in, const int* in_sizes, int n_in,
                              void* d_out, int out_size, void* d_ws, size_t ws_size,
                              hipStream_t stream) {
  const float* x     = (const float*)d_in[0];
  const float* wqkv  = (const float*)d_in[1];
  const float* bqkv  = (const float*)d_in[2];
  const float* wout  = (const float*)d_in[3];
  const float* bout  = (const float*)d_in[4];
  const float* abias = (const float*)d_in[5];
  const void*  mask  = d_in[6];

  __hip_bfloat16* ws  = (__hip_bfloat16*)d_ws;
  __hip_bfloat16* xb  = ws;              // x bf16            [4096][1024]  (8 MB)
  __hip_bfloat16* wqb = ws + 4194304;    // Wqkv bf16         [3072][1024]  (6 MB)
  __hip_bfloat16* owb = ws + 7340032;    // out_w bf16        [1024][1024]  (2 MB)
  __hip_bfloat16* qkb = ws + 8388608;    // q|k bf16          [4096][2048]  (16 MB)
  __hip_bfloat16* vtb = ws + 16777216;   // V^T bf16          [2][16][64][2048] (8 MB)
  __hip_bfloat16* aob = xb;              // attn out bf16 overlays xb (dead after gemm1)

  cvt_f32_bf16<<<4096, 256, 0, stream>>>(x, xb, 1048576);
  cvt_f32_bf16<<<3072, 256, 0, stream>>>(wqkv, wqb, 786432);
  cvt_f32_bf16<<<1024, 256, 0, stream>>>(wout, owb, 262144);
  gemm_bt<0><<<dim3(32, 24), 256, 0, stream>>>(xb, wqb, bqkv, (void*)qkb, vtb,
                                               4096, 3072, 1024);
  attn_fwd<<<dim3(16, 32), 512, 0, stream>>>(qkb, vtb, abias, mask, aob);
  gemm_bt<1><<<dim3(32, 8), 256, 0, stream>>>(aob, owb, bout, d_out,
                                              (__hip_bfloat16*)nullptr, 4096, 1024, 1024);
}